// Round 1
// baseline (655.675 us; speedup 1.0000x reference)
//
#include <hip/hip_runtime.h>
#include <hip/hip_bf16.h>

// Problem constants (fixed by the reference)
constexpr int M_ = 8192;      // batch
constexpr int N_ = 4096;      // out_dim
constexpr int K_ = 4096;      // in_dim
constexpr int CBOOK = 65536;
constexpr int HA = 10007, HB = 20011;
constexpr int HC3 = 3 * 40009;     // 120027
// sign hash: all constants odd => sign = +1 iff (o+i) even

// Key algebraic identity (CBOOK = 2^16, HB odd => invertible mod 2^16):
//   HB^{-1} mod 2^16 = 131;  C0 = HA * 131 mod 2^16 = 197  (197*HB ≡ HA)
//   idx(n,k) = (n*HA + k*HB + HC3) & 0xFFFF = (u*HB + HC3) & 0xFFFF,
//     with u = (197n + k) & 0xFFFF.   Parity: u ≡ n+k (mod 2).
//   => W[n][k] = P2[(197n + k) & 0xFFFF],
//      P2[u] = (u&1 ? -1 : +1) * cb[(u*HB + HC3) & 0xFFFF]
// The whole 32 MiB weight matrix is windows of one 128 KB periodic sequence.
constexpr int C0 = 197;

// GEMM tiling: block 256x128, 4 waves stacked (wave tile 64x128), BK=64.
// A (x, bf16) goes through double-buffered LDS (each wave reads only its own
// rows).  B (W) is read straight global->VGPR from phase-shifted copies of
// the P2 sequence (1.1 MB, L2-resident on every XCD) -> zero LDS for B and
// no materialized weight matrix at all.
constexpr int BM = 256, BN = 128, BK = 64;
constexpr int KITERS = K_ / BK;            // 64

using bf16x8 = __bf16 __attribute__((ext_vector_type(8)));
using f32x4  = float __attribute__((ext_vector_type(4)));
using u16x8  = unsigned short __attribute__((ext_vector_type(8)));

typedef __attribute__((address_space(3))) void lds_void_t;
typedef const __attribute__((address_space(1))) void gbl_void_t;

static __device__ __forceinline__ unsigned short f2bf(float f) {
    __bf16 h = (__bf16)f;   // RNE on gfx950
    return __builtin_bit_cast(unsigned short, h);
}

// ---------------------------------------------------------------------------
// P2 phase-copy table:
//   P2p[p][i] = P2ext[i + p],  p in [0,8), i in [0,PADE)
//   P2ext[u] = (u&1 ? -1:+1) * cb[(u*HB + HC3) & 0xFFFF]   (periodic formula,
//              valid for u >= 65536 directly since the mod is inside)
// Max element needed: e<=65535 rounded down to 8 plus k up to 4095+7
//   => i_max = 65528 + 4095 < PADE.  PADE multiple of 8 -> rows 16B aligned.
// ---------------------------------------------------------------------------
constexpr int PADE  = 69640;                 // per-phase elements
constexpr int PTOT  = 8 * PADE;              // 557120
constexpr int PB    = (PTOT + 255) / 256;    // 2177 blocks
constexpr int CONVB = M_ * K_ / 8 / 256;     // 16384 blocks (x fp32 -> bf16)

__global__ __launch_bounds__(256) void prep_kernel(const float* __restrict__ x,
                                                   const float* __restrict__ cb,
                                                   unsigned short* __restrict__ P2p,
                                                   unsigned short* __restrict__ xb) {
    const int b = blockIdx.x;
    if (b < PB) {
        const int t = b * 256 + threadIdx.x;
        if (t < PTOT) {
            const int p = t / PADE;          // 0..7
            const int i = t - p * PADE;
            const int u = i + p;             // <= 69646; u*HB < 2^31
            float v = cb[(u * HB + HC3) & (CBOOK - 1)];
            if (u & 1) v = -v;
            P2p[t] = f2bf(v);                // layout [8][PADE], t = p*PADE+i
        }
    } else {
        const size_t t = (size_t)(b - PB) * 256 + threadIdx.x;
        const float4* p = reinterpret_cast<const float4*>(x) + t * 2;
        const float4 a = p[0], c = p[1];
        u16x8 out;
        out[0] = f2bf(a.x); out[1] = f2bf(a.y); out[2] = f2bf(a.z); out[3] = f2bf(a.w);
        out[4] = f2bf(c.x); out[5] = f2bf(c.y); out[6] = f2bf(c.z); out[7] = f2bf(c.w);
        reinterpret_cast<u16x8*>(xb)[t] = out;
    }
}

// ---------------------------------------------------------------------------
// GEMM: C[M][N] = A[M][K] * W[N][K]^T + bias
// B-fragment for mfma_f32_16x16x32_bf16: lane holds W[n][k..k+8),
//   n = ntile*16 + (lane&15), k = i*64 + kk*32 + (lane>>4)*8.
// Element index E = e + k, e = (197n)&0xFFFF.  Phase p = e&7 is fixed per
// (lane,nt); within phase p, E lives at i = ((e>>3)<<3) + k  (16B aligned).
// ---------------------------------------------------------------------------
__global__ __launch_bounds__(256, 2) void gemm_kernel(
        const unsigned short* __restrict__ A,    // xb row-major [M][K]
        const unsigned short* __restrict__ P2p,  // [8][PADE] phase table
        const float* __restrict__ bias,
        float* __restrict__ C) {
    __shared__ __align__(16) unsigned short ldsA[2][BM * BK];  // 2 x 32 KB

    const int tid  = threadIdx.x;
    const int lane = tid & 63;
    const int wv   = tid >> 6;      // wave 0..3 -> A row strip wv*64
    const int m0 = blockIdx.y * BM;
    const int n0 = blockIdx.x * BN;

    const int quad = lane >> 4;     // 0..3
    const int l16  = lane & 15;
    const int lr = lane >> 3;       // staging: row in 8-row group
    const int lc = lane & 7;        // staging: 16B block in 128B row
    const int scol = (lc ^ lr) * 8; // xor-swizzled source column (elements)
    const int sw   = l16 & 7;       // frag-read swizzle key (row&7 == l16&7)

    // lane's global A base (row m0 + lr; inst r adds wv*64 + r*8 rows)
    const unsigned short* aLane = A + (size_t)(m0 + lr) * K_ + scol;
    const char* p2b = reinterpret_cast<const char*>(P2p);
    const int ntile0 = n0 >> 4;

    // per-nt B base byte offsets (includes phase row + aligned block + quad*8)
    int boff[8];
#pragma unroll
    for (int nt = 0; nt < 8; ++nt) {
        const int n = ((ntile0 + nt) << 4) + l16;
        const int e = (C0 * n) & (CBOOK - 1);
        boff[nt] = ((e & 7) * PADE + ((e >> 3) << 3) + quad * 8) * 2;
    }

    f32x4 acc[4][8] = {};           // [mt][nt] -> 128 VGPRs

    // stage k-iter 0 into buffer 0
#pragma unroll
    for (int r = 0; r < 8; ++r) {
        const int rowb = wv * 64 + r * 8;   // wave-uniform
        __builtin_amdgcn_global_load_lds(
            (gbl_void_t*)(aLane + (size_t)rowb * K_),
            (lds_void_t*)&ldsA[0][rowb * BK], 16, 0, 0);
    }

    for (int i = 0; i < KITERS; ++i) {
        __syncthreads();            // A(i) staged; all waves done with buf^1
        const int buf = i & 1;

        // stage A(i+1) into the other buffer (overlaps this iter's MFMAs)
        if (i + 1 < KITERS) {
            const unsigned short* aNext = aLane + (size_t)(i + 1) * BK;
#pragma unroll
            for (int r = 0; r < 8; ++r) {
                const int rowb = wv * 64 + r * 8;
                __builtin_amdgcn_global_load_lds(
                    (gbl_void_t*)(aNext + (size_t)rowb * K_),
                    (lds_void_t*)&ldsA[buf ^ 1][rowb * BK], 16, 0, 0);
            }
        }

        // B fragments for both k32 halfsteps, straight from L2 (16B/lane)
        bf16x8 bfr[2][8];
#pragma unroll
        for (int kk = 0; kk < 2; ++kk)
#pragma unroll
            for (int nt = 0; nt < 8; ++nt)
                bfr[kk][nt] = *reinterpret_cast<const bf16x8*>(
                    p2b + boff[nt] + (i * 64 + kk * 32) * 2);

#pragma unroll
        for (int kk = 0; kk < 2; ++kk) {
            bf16x8 af[4];
            const int blk = ((kk * 4 + quad) ^ sw) * 8;  // swizzled 16B block
#pragma unroll
            for (int mt = 0; mt < 4; ++mt)
                af[mt] = *reinterpret_cast<const bf16x8*>(
                    &ldsA[buf][(wv * 64 + mt * 16 + l16) * BK + blk]);
#pragma unroll
            for (int mt = 0; mt < 4; ++mt)
#pragma unroll
                for (int nt = 0; nt < 8; ++nt)
                    acc[mt][nt] = __builtin_amdgcn_mfma_f32_16x16x32_bf16(
                        af[mt], bfr[kk][nt], acc[mt][nt], 0, 0, 0);
        }
    }

    // epilogue: C/D layout col=lane&15, row=quad*4+r (m89/m91-verified)
#pragma unroll
    for (int nt = 0; nt < 8; ++nt) {
        const int col = n0 + nt * 16 + l16;
        const float bv = bias[col];
#pragma unroll
        for (int mt = 0; mt < 4; ++mt) {
            const int rowb = m0 + wv * 64 + mt * 16 + quad * 4;
#pragma unroll
            for (int r = 0; r < 4; ++r)
                C[(size_t)(rowb + r) * N_ + col] = acc[mt][nt][r] + bv;
        }
    }
}

// ---------------------------------------------------------------------------
// Correctness-insurance fallback (only if ws too small; slow but exact)
// ---------------------------------------------------------------------------
__global__ __launch_bounds__(256) void naive_kernel(const float* __restrict__ x,
                                                    const float* __restrict__ cb,
                                                    const float* __restrict__ bias,
                                                    float* __restrict__ out) {
    const size_t t = (size_t)blockIdx.x * 256 + threadIdx.x;
    const int row = (int)(t / N_);
    const int col = (int)(t % N_);
    float s = bias[col];
    const float* xr = x + (size_t)row * K_;
    const int h = col * HA + HC3;
    for (int i = 0; i < K_; ++i) {
        float v = cb[(h + i * HB) & (CBOOK - 1)];
        s += xr[i] * (((col ^ i) & 1) ? -v : v);
    }
    out[t] = s;
}

extern "C" void kernel_launch(void* const* d_in, const int* in_sizes, int n_in,
                              void* d_out, int out_size, void* d_ws, size_t ws_size,
                              hipStream_t stream) {
    const float* x    = (const float*)d_in[0];
    const float* cb   = (const float*)d_in[1];
    const float* bias = (const float*)d_in[2];
    float* out = (float*)d_out;

    const size_t pBytes = (size_t)PTOT * sizeof(unsigned short);     // ~1.09 MiB
    const size_t xBytes = (size_t)M_ * K_ * sizeof(unsigned short);  // 64 MiB

    if (ws_size >= pBytes + xBytes) {
        unsigned short* P2p = (unsigned short*)d_ws;
        unsigned short* xb  = (unsigned short*)((char*)d_ws + pBytes);  // 16B-aligned
        prep_kernel<<<PB + CONVB, 256, 0, stream>>>(x, cb, P2p, xb);
        gemm_kernel<<<dim3(N_ / BN, M_ / BM), 256, 0, stream>>>(xb, P2p, bias, out);
    } else {
        naive_kernel<<<(int)((size_t)M_ * N_ / 256), 256, 0, stream>>>(x, cb, bias, out);
    }
}

// Round 2
// 463.128 us; speedup vs baseline: 1.4158x; 1.4158x over previous
//
#include <hip/hip_runtime.h>
#include <hip/hip_bf16.h>

// Problem constants (fixed by the reference)
constexpr int M_ = 8192;      // batch
constexpr int N_ = 4096;      // out_dim
constexpr int K_ = 4096;      // in_dim
constexpr int CBOOK = 65536;
constexpr int HA = 10007, HB = 20011;
constexpr int HC3 = 3 * 40009;     // 120027
// sign hash: all constants odd => sign = +1 iff (o+i) even

// ---------------------------------------------------------------------------
// GEMM tiling: 256x256 tile, BK=32, 512 threads (8 waves as 2(M) x 4(N),
// wave tile 128x64).  BOTH operands LDS-staged (fixes the 4x-redundant B
// L2 traffic of the previous 128-wide design: 131 FLOP per L2 byte now).
// 3-deep LDS ring (3 x (16KB A + 16KB B) = 96KB) + raw s_barrier + counted
// vmcnt(4): staging is issued 2 K-tiles ahead and never drained to 0 in the
// main loop (T3+T4).  W is pre-generated in the EXACT linear LDS image
// (bank swizzle baked in), so B staging is fully coalesced global_load_lds.
// ---------------------------------------------------------------------------
constexpr int BM = 256, BN = 256, BK = 32;
constexpr int NKT = K_ / BK;               // 128 K-tiles

using bf16x8 = __bf16 __attribute__((ext_vector_type(8)));
using f32x4  = float __attribute__((ext_vector_type(4)));
using u16x8  = unsigned short __attribute__((ext_vector_type(8)));

typedef __attribute__((address_space(3))) void lds_void_t;
typedef const __attribute__((address_space(1))) void gbl_void_t;

static __device__ __forceinline__ unsigned short f2bf(float f) {
    __bf16 h = (__bf16)f;   // RNE on gfx950
    return __builtin_bit_cast(unsigned short, h);
}

// ---------------------------------------------------------------------------
// Merged prologue.
//   blocks [0, GENB): W in LDS-image order.  Global 16B-slot id t:
//     slot = t & 1023, kt = (t>>10) & 127, nb = t>>17
//     row  = slot>>2 (n within 256-strip), blk = slot&3, key = (row>>1)&3
//     holds W[nb*256+row][kt*32 + ((blk^key)<<3) .. +8)   (swizzle baked in)
//   blocks [GENB, GENB+CONVB): x fp32 -> bf16 row-major (A staging source)
// ---------------------------------------------------------------------------
constexpr int GENB  = N_ * K_ / 8 / 256;   // 8192
constexpr int CONVB = M_ * K_ / 8 / 256;   // 16384

__global__ __launch_bounds__(256) void prep_kernel(const float* __restrict__ x,
                                                   const float* __restrict__ cb,
                                                   unsigned short* __restrict__ Wf,
                                                   unsigned short* __restrict__ xb) {
    const int b = blockIdx.x;
    if (b < GENB) {
        const int t    = b * 256 + threadIdx.x;   // [0, 2^21) 16B slots
        const int slot = t & 1023;
        const int kt   = (t >> 10) & 127;
        const int nb   = t >> 17;
        const int row  = slot >> 2;
        const int key  = (row >> 1) & 3;
        const int n  = (nb << 8) + row;
        const int k0 = (kt << 5) + (((slot & 3) ^ key) << 3);
        const int h  = n * HA + k0 * HB + HC3;    // < 2^27, no overflow
        u16x8 out;
#pragma unroll
        for (int j = 0; j < 8; ++j) {
            const int idx = (h + j * HB) & (CBOOK - 1);
            float v = cb[idx];
            v = ((n ^ (k0 + j)) & 1) ? -v : v;
            out[j] = f2bf(v);
        }
        *reinterpret_cast<u16x8*>(&Wf[(size_t)t * 8]) = out;   // coalesced
    } else {
        const size_t t = (size_t)(b - GENB) * 256 + threadIdx.x;
        const float4* p = reinterpret_cast<const float4*>(x) + t * 2;
        const float4 a = p[0], c = p[1];
        u16x8 out;
        out[0] = f2bf(a.x); out[1] = f2bf(a.y); out[2] = f2bf(a.z); out[3] = f2bf(a.w);
        out[4] = f2bf(c.x); out[5] = f2bf(c.y); out[6] = f2bf(c.z); out[7] = f2bf(c.w);
        reinterpret_cast<u16x8*>(xb)[t] = out;
    }
}

// ---------------------------------------------------------------------------
// GEMM: C[M][N] = A[M][K] * W[N][K]^T + bias
// ---------------------------------------------------------------------------
__global__ __launch_bounds__(512, 2) void gemm_kernel(
        const unsigned short* __restrict__ A,    // xb row-major [M][K]
        const unsigned short* __restrict__ Wf,   // LDS-image W
        const float* __restrict__ bias,
        float* __restrict__ C) {
    // 3-ring: A[3][256*32] then B[3][256*32] u16 = 96 KB total
    __shared__ __align__(16) unsigned short sm[3 * 8192 * 2];
    unsigned short* As = sm;
    unsigned short* Bs = sm + 3 * 8192;

    const int tid  = threadIdx.x;
    const int lane = tid & 63;
    const int w    = tid >> 6;          // wave 0..7
    const int wm   = w >> 2;            // 0..1 -> rows wm*128
    const int wn   = w & 3;             // 0..3 -> cols wn*64
    const int m0 = blockIdx.y * BM;
    const int n0 = blockIdx.x * BN;

    const int quad = lane >> 4;         // 0..3
    const int l16  = lane & 15;

    // --- staging addressing ---
    // slot s = r*512 + tid: row = s>>2, blk = s&3; swizzle key = (row>>1)&3
    const int sblk = (lane & 3) ^ ((lane >> 3) & 3);
    const unsigned short* aLane =
        A + (size_t)(m0 + w * 16 + (lane >> 2)) * K_ + sblk * 8;
    const unsigned short* bLane =
        Wf + (size_t)blockIdx.x * NKT * 8192 + tid * 8;   // fully linear

    // --- ds-read addressing (swizzled, 2-way max -> conflict-free) ---
    const int rblk = (quad ^ ((l16 >> 1) & 3)) * 8;
    const unsigned short* aRd = As + (wm * 128 + l16) * 32 + rblk;
    const unsigned short* bRd = Bs + (wn * 64 + l16) * 32 + rblk;

    f32x4 acc[8][4] = {};               // wave tile 128x64

    auto STAGE = [&](int kt, int bs) {
#pragma unroll
        for (int r = 0; r < 2; ++r) {
            __builtin_amdgcn_global_load_lds(
                (gbl_void_t*)(aLane + (size_t)r * 128 * K_ + (size_t)kt * BK),
                (lds_void_t*)(As + bs * 8192 + (r * 512 + w * 64) * 8), 16, 0, 0);
            __builtin_amdgcn_global_load_lds(
                (gbl_void_t*)(bLane + (size_t)kt * 8192 + r * 4096),
                (lds_void_t*)(Bs + bs * 8192 + (r * 512 + w * 64) * 8), 16, 0, 0);
        }
    };

    STAGE(0, 0);
    STAGE(1, 1);

    int bC = 0;                          // compute buffer = kt % 3
    for (int kt = 0; kt < NKT; ++kt) {
        // Certify own ds_reads retired and own stage(kt) landed; keep the
        // newest stage (kt+1, 4 loads) in flight across the barrier (T4).
        asm volatile("s_waitcnt lgkmcnt(0)" ::: "memory");
        if (kt < NKT - 1) asm volatile("s_waitcnt vmcnt(4)" ::: "memory");
        else              asm volatile("s_waitcnt vmcnt(0)" ::: "memory");
        __builtin_amdgcn_s_barrier();            // raw: no vmem drain
        __builtin_amdgcn_sched_barrier(0);       // no hoisting across barrier

        if (kt + 2 < NKT) {                      // stage 2 tiles ahead
            int bS = bC + 2; if (bS >= 3) bS -= 3;
            STAGE(kt + 2, bS);
        }

        bf16x8 bfr[4], afr[8];
#pragma unroll
        for (int nt = 0; nt < 4; ++nt)
            bfr[nt] = *reinterpret_cast<const bf16x8*>(bRd + bC * 8192 + nt * 512);
#pragma unroll
        for (int mt = 0; mt < 8; ++mt)
            afr[mt] = *reinterpret_cast<const bf16x8*>(aRd + bC * 8192 + mt * 512);

        __builtin_amdgcn_s_setprio(1);
#pragma unroll
        for (int mt = 0; mt < 8; ++mt)
#pragma unroll
            for (int nt = 0; nt < 4; ++nt)
                acc[mt][nt] = __builtin_amdgcn_mfma_f32_16x16x32_bf16(
                    afr[mt], bfr[nt], acc[mt][nt], 0, 0, 0);
        __builtin_amdgcn_s_setprio(0);

        ++bC; if (bC == 3) bC = 0;
    }

    // epilogue: C/D layout col=lane&15, row=quad*4+r (m89/m91-verified)
#pragma unroll
    for (int nt = 0; nt < 4; ++nt) {
        const int col = n0 + wn * 64 + nt * 16 + l16;
        const float bv = bias[col];
#pragma unroll
        for (int mt = 0; mt < 8; ++mt) {
            const int rowb = m0 + wm * 128 + mt * 16 + quad * 4;
#pragma unroll
            for (int r = 0; r < 4; ++r)
                C[(size_t)(rowb + r) * N_ + col] = acc[mt][nt][r] + bv;
        }
    }
}

// ---------------------------------------------------------------------------
// Correctness-insurance fallback (only if ws too small; slow but exact)
// ---------------------------------------------------------------------------
__global__ __launch_bounds__(256) void naive_kernel(const float* __restrict__ x,
                                                    const float* __restrict__ cb,
                                                    const float* __restrict__ bias,
                                                    float* __restrict__ out) {
    const size_t t = (size_t)blockIdx.x * 256 + threadIdx.x;
    const int row = (int)(t / N_);
    const int col = (int)(t % N_);
    float s = bias[col];
    const float* xr = x + (size_t)row * K_;
    const int h = col * HA + HC3;
    for (int i = 0; i < K_; ++i) {
        float v = cb[(h + i * HB) & (CBOOK - 1)];
        s += xr[i] * (((col ^ i) & 1) ? -v : v);
    }
    out[t] = s;
}

extern "C" void kernel_launch(void* const* d_in, const int* in_sizes, int n_in,
                              void* d_out, int out_size, void* d_ws, size_t ws_size,
                              hipStream_t stream) {
    const float* x    = (const float*)d_in[0];
    const float* cb   = (const float*)d_in[1];
    const float* bias = (const float*)d_in[2];
    float* out = (float*)d_out;

    const size_t wBytes = (size_t)N_ * K_ * sizeof(unsigned short);  // 32 MiB
    const size_t xBytes = (size_t)M_ * K_ * sizeof(unsigned short);  // 64 MiB

    if (ws_size >= wBytes + xBytes) {
        unsigned short* Wf = (unsigned short*)d_ws;
        unsigned short* xb = (unsigned short*)((char*)d_ws + wBytes);
        prep_kernel<<<GENB + CONVB, 256, 0, stream>>>(x, cb, Wf, xb);
        // grid x = 16 n-strips: XCD = linear%8; each XCD's Wf slice is
        // 2 strips x 2MB = 4MB = its L2.  B stream stays L2-resident.
        gemm_kernel<<<dim3(N_ / BN, M_ / BM), 512, 0, stream>>>(xb, Wf, bias, out);
    } else {
        naive_kernel<<<(int)((size_t)M_ * N_ / 256), 256, 0, stream>>>(x, cb, bias, out);
    }
}

// Round 3
// 451.781 us; speedup vs baseline: 1.4513x; 1.0251x over previous
//
#include <hip/hip_runtime.h>
#include <hip/hip_bf16.h>

// Problem constants (fixed by the reference)
constexpr int M_ = 8192;      // batch
constexpr int N_ = 4096;      // out_dim
constexpr int K_ = 4096;      // in_dim
constexpr int CBOOK = 65536;
constexpr int HA = 10007, HB = 20011;
constexpr int HC3 = 3 * 40009;     // 120027
// sign hash: all constants odd => sign = +1 iff (o+i) even

// Algebra (CBOOK = 2^16, HB odd => invertible mod 2^16):
//   197*HB ≡ HA (mod 2^16)  =>  idx(n,k) = (U*HB + HC3) & 0xFFFF,
//   U = (197n + k) & 0xFFFF; parity(U) = parity(n+k) => sign folds into U.
//   W[n][k] = P2ext[(197n+k) & 0xFFFF],
//   P2ext[u] = (u&1 ? -1 : +1) * cb[(u*HB + HC3) & 0xFFFF]   (65536-periodic)
// Used ONLY in prep (to turn 8 scattered cb gathers into 1 aligned 16B load);
// the GEMM still reads a linear pre-swizzled W image.
constexpr int C0 = 197;

constexpr int BM = 256, BN = 256, BK = 32;
constexpr int NKT = K_ / BK;               // 128 K-tiles

using bf16x8 = __bf16 __attribute__((ext_vector_type(8)));
using f32x4  = float __attribute__((ext_vector_type(4)));
using u16x8  = unsigned short __attribute__((ext_vector_type(8)));

typedef __attribute__((address_space(3))) void lds_void_t;
typedef const __attribute__((address_space(1))) void gbl_void_t;

static __device__ __forceinline__ unsigned short f2bf(float f) {
    __bf16 h = (__bf16)f;   // RNE on gfx950
    return __builtin_bit_cast(unsigned short, h);
}

// ---------------------------------------------------------------------------
// prep stage 1: P2 phase-copy table  P2p[p][i] = P2ext[i+p], p<8, i<65536.
// 1 MiB; gives every (lane,slot) a 16B-aligned contiguous window of P2ext.
// ---------------------------------------------------------------------------
constexpr int P2N   = 8 * 65536;           // 524288 elems, 1 MiB
constexpr int P2B   = P2N / 256;           // 2048 blocks

__global__ __launch_bounds__(256) void prep_p2(const float* __restrict__ cb,
                                               unsigned short* __restrict__ P2p) {
    const int t = blockIdx.x * 256 + threadIdx.x;   // [0, 2^19)
    const int p = t >> 16;
    const int i = t & 65535;
    const int u = i + p;                            // u*HB < 2^31
    float v = cb[(u * HB + HC3) & (CBOOK - 1)];
    if (u & 1) v = -v;
    P2p[t] = f2bf(v);
}

// ---------------------------------------------------------------------------
// prep stage 2 (merged):
//   blocks [0, GENB): W in LDS-image order (swizzle baked in), via P2p:
//     slot t: row = (t&1023)>>2, blk = t&3, kt = (t>>10)&127, nb = t>>17
//     key = (row>>1)&3; n = nb*256+row; k0 = kt*32 + ((blk^key)<<3)
//     u0 = (197n + k0) & 0xFFFF;  out[j] = P2ext[u0+j] = P2p[u0&7][u0&~7 + j]
//   blocks [GENB, GENB+CONVB): x fp32 -> bf16 row-major (A staging source)
// ---------------------------------------------------------------------------
constexpr int GENB  = N_ * K_ / 8 / 256;   // 8192
constexpr int CONVB = M_ * K_ / 8 / 256;   // 16384

__global__ __launch_bounds__(256) void prep_main(const float* __restrict__ x,
                                                 const unsigned short* __restrict__ P2p,
                                                 unsigned short* __restrict__ Wf,
                                                 unsigned short* __restrict__ xb) {
    const int b = blockIdx.x;
    if (b < GENB) {
        const int t    = b * 256 + threadIdx.x;   // [0, 2^21) 16B slots
        const int slot = t & 1023;
        const int kt   = (t >> 10) & 127;
        const int nb   = t >> 17;
        const int row  = slot >> 2;
        const int key  = (row >> 1) & 3;
        const int n  = (nb << 8) + row;
        const int k0 = (kt << 5) + (((slot & 3) ^ key) << 3);
        const int u0 = (C0 * n + k0) & (CBOOK - 1);
        const u16x8 w = *reinterpret_cast<const u16x8*>(
            P2p + ((u0 & 7) << 16) + (u0 & 65528));     // one aligned 16B load
        *reinterpret_cast<u16x8*>(&Wf[(size_t)t * 8]) = w;   // coalesced
    } else {
        const size_t t = (size_t)(b - GENB) * 256 + threadIdx.x;
        const float4* p = reinterpret_cast<const float4*>(x) + t * 2;
        const float4 a = p[0], c = p[1];
        u16x8 out;
        out[0] = f2bf(a.x); out[1] = f2bf(a.y); out[2] = f2bf(a.z); out[3] = f2bf(a.w);
        out[4] = f2bf(c.x); out[5] = f2bf(c.y); out[6] = f2bf(c.z); out[7] = f2bf(c.w);
        reinterpret_cast<u16x8*>(xb)[t] = out;
    }
}

// ---------------------------------------------------------------------------
// GEMM: C[M][N] = A[M][K] * W[N][K]^T + bias
// 256x256 tile, BK=32, 512 threads (8 waves 2Mx4N, wave tile 128x64).
// 3-deep LDS ring (96 KB), counted vmcnt(4) cert before the window-open
// barrier (T4, proven in R2).  NEW: each K-window is split into 2 phases
// {ds_read subtile + 2 stage loads -> barrier -> lgkm0 -> 16 MFMA in
// setprio -> barrier} (T3 per-phase interleave + T5 role-split).
// ---------------------------------------------------------------------------
__global__ __launch_bounds__(512, 2) void gemm_kernel(
        const unsigned short* __restrict__ A,    // xb row-major [M][K]
        const unsigned short* __restrict__ Wf,   // LDS-image W
        const float* __restrict__ bias,
        float* __restrict__ C) {
    __shared__ __align__(16) unsigned short sm[3 * 8192 * 2];  // 96 KB
    unsigned short* As = sm;
    unsigned short* Bs = sm + 3 * 8192;

    const int tid  = threadIdx.x;
    const int lane = tid & 63;
    const int w    = tid >> 6;          // wave 0..7
    const int wm   = w >> 2;            // 0..1 -> rows wm*128
    const int wn   = w & 3;             // 0..3 -> cols wn*64
    const int m0 = blockIdx.y * BM;
    const int n0 = blockIdx.x * BN;

    const int quad = lane >> 4;         // 0..3
    const int l16  = lane & 15;

    // --- staging addressing (slot s = r*512 + tid: row=s>>2, blk=s&3,
    //     swizzle key=(row>>1)&3 baked into both source layouts) ---
    const int sblk = (lane & 3) ^ ((lane >> 3) & 3);
    const unsigned short* aLane =
        A + (size_t)(m0 + w * 16 + (lane >> 2)) * K_ + sblk * 8;
    const unsigned short* bLane =
        Wf + (size_t)blockIdx.x * NKT * 8192 + tid * 8;   // fully linear

    // --- ds-read addressing (swizzled, 2-way max -> conflict-free) ---
    const int rblk = (quad ^ ((l16 >> 1) & 3)) * 8;
    const unsigned short* aRd = As + (wm * 128 + l16) * 32 + rblk;
    const unsigned short* bRd = Bs + (wn * 64 + l16) * 32 + rblk;

    f32x4 acc[8][4] = {};               // wave tile 128x64

    // stage half r (A row-half r + B half r) of K-tile kt into ring slot bs
    auto STAGE_HALF = [&](int kt, int bs, int r) {
        __builtin_amdgcn_global_load_lds(
            (gbl_void_t*)(aLane + (size_t)r * 128 * K_ + (size_t)kt * BK),
            (lds_void_t*)(As + bs * 8192 + (r * 512 + w * 64) * 8), 16, 0, 0);
        __builtin_amdgcn_global_load_lds(
            (gbl_void_t*)(bLane + (size_t)kt * 8192 + r * 4096),
            (lds_void_t*)(Bs + bs * 8192 + (r * 512 + w * 64) * 8), 16, 0, 0);
    };

    STAGE_HALF(0, 0, 0); STAGE_HALF(0, 0, 1);
    STAGE_HALF(1, 1, 0); STAGE_HALF(1, 1, 1);
    asm volatile("s_waitcnt vmcnt(4)" ::: "memory");   // K-tile 0 landed
    __builtin_amdgcn_s_barrier();                      // open window 0
    __builtin_amdgcn_sched_barrier(0);

    int bC = 0;                          // compute buffer = kt % 3
    for (int kt = 0; kt < NKT; ++kt) {
        int bS = bC + 2; if (bS >= 3) bS -= 3;
        const bool st = (kt + 2 < NKT);

        // ---- phase 0: B all + A rows 0-127; MFMA mt0-3 ----
        bf16x8 bfr[4], afr0[4];
#pragma unroll
        for (int nt = 0; nt < 4; ++nt)
            bfr[nt] = *reinterpret_cast<const bf16x8*>(bRd + bC * 8192 + nt * 512);
#pragma unroll
        for (int mt = 0; mt < 4; ++mt)
            afr0[mt] = *reinterpret_cast<const bf16x8*>(aRd + bC * 8192 + mt * 512);
        if (st) STAGE_HALF(kt + 2, bS, 0);
        __builtin_amdgcn_sched_barrier(0);
        __builtin_amdgcn_s_barrier();
        asm volatile("s_waitcnt lgkmcnt(0)" ::: "memory");
        __builtin_amdgcn_sched_barrier(0);
        __builtin_amdgcn_s_setprio(1);
#pragma unroll
        for (int mt = 0; mt < 4; ++mt)
#pragma unroll
            for (int nt = 0; nt < 4; ++nt)
                acc[mt][nt] = __builtin_amdgcn_mfma_f32_16x16x32_bf16(
                    afr0[mt], bfr[nt], acc[mt][nt], 0, 0, 0);
        __builtin_amdgcn_s_setprio(0);
        __builtin_amdgcn_sched_barrier(0);
        __builtin_amdgcn_s_barrier();
        __builtin_amdgcn_sched_barrier(0);

        // ---- phase 1: A rows 128-255; MFMA mt4-7 ----
        bf16x8 afr1[4];
#pragma unroll
        for (int mt = 0; mt < 4; ++mt)
            afr1[mt] = *reinterpret_cast<const bf16x8*>(aRd + bC * 8192 + (mt + 4) * 512);
        if (st) STAGE_HALF(kt + 2, bS, 1);
        __builtin_amdgcn_sched_barrier(0);
        __builtin_amdgcn_s_barrier();
        asm volatile("s_waitcnt lgkmcnt(0)" ::: "memory");
        __builtin_amdgcn_sched_barrier(0);
        __builtin_amdgcn_s_setprio(1);
#pragma unroll
        for (int mt = 0; mt < 4; ++mt)
#pragma unroll
            for (int nt = 0; nt < 4; ++nt)
                acc[mt + 4][nt] = __builtin_amdgcn_mfma_f32_16x16x32_bf16(
                    afr1[mt], bfr[nt], acc[mt + 4][nt], 0, 0, 0);
        __builtin_amdgcn_s_setprio(0);
        __builtin_amdgcn_sched_barrier(0);

        // ---- window close / open next: certify stage(kt+1) landed ----
        if (kt < NKT - 1) {
            if (st) asm volatile("s_waitcnt vmcnt(4)" ::: "memory");
            else    asm volatile("s_waitcnt vmcnt(0)" ::: "memory");
            __builtin_amdgcn_s_barrier();
            __builtin_amdgcn_sched_barrier(0);
        }

        ++bC; if (bC == 3) bC = 0;
    }

    // epilogue: C/D layout col=lane&15, row=quad*4+r (m89/m91-verified)
#pragma unroll
    for (int nt = 0; nt < 4; ++nt) {
        const int col = n0 + wn * 64 + nt * 16 + l16;
        const float bv = bias[col];
#pragma unroll
        for (int mt = 0; mt < 8; ++mt) {
            const int rowb = m0 + wm * 128 + mt * 16 + quad * 4;
#pragma unroll
            for (int r = 0; r < 4; ++r)
                C[(size_t)(rowb + r) * N_ + col] = acc[mt][nt][r] + bv;
        }
    }
}

// ---------------------------------------------------------------------------
// Correctness-insurance fallback (only if ws too small; slow but exact)
// ---------------------------------------------------------------------------
__global__ __launch_bounds__(256) void naive_kernel(const float* __restrict__ x,
                                                    const float* __restrict__ cb,
                                                    const float* __restrict__ bias,
                                                    float* __restrict__ out) {
    const size_t t = (size_t)blockIdx.x * 256 + threadIdx.x;
    const int row = (int)(t / N_);
    const int col = (int)(t % N_);
    float s = bias[col];
    const float* xr = x + (size_t)row * K_;
    const int h = col * HA + HC3;
    for (int i = 0; i < K_; ++i) {
        float v = cb[(h + i * HB) & (CBOOK - 1)];
        s += xr[i] * (((col ^ i) & 1) ? -v : v);
    }
    out[t] = s;
}

extern "C" void kernel_launch(void* const* d_in, const int* in_sizes, int n_in,
                              void* d_out, int out_size, void* d_ws, size_t ws_size,
                              hipStream_t stream) {
    const float* x    = (const float*)d_in[0];
    const float* cb   = (const float*)d_in[1];
    const float* bias = (const float*)d_in[2];
    float* out = (float*)d_out;

    const size_t wBytes = (size_t)N_ * K_ * sizeof(unsigned short);  // 32 MiB
    const size_t xBytes = (size_t)M_ * K_ * sizeof(unsigned short);  // 64 MiB
    const size_t pBytes = (size_t)P2N * sizeof(unsigned short);      // 1 MiB

    if (ws_size >= wBytes + xBytes + pBytes) {
        unsigned short* Wf  = (unsigned short*)d_ws;
        unsigned short* xb  = (unsigned short*)((char*)d_ws + wBytes);
        unsigned short* P2p = (unsigned short*)((char*)d_ws + wBytes + xBytes);
        prep_p2<<<P2B, 256, 0, stream>>>(cb, P2p);
        prep_main<<<GENB + CONVB, 256, 0, stream>>>(x, P2p, Wf, xb);
        // grid x = 16 n-strips: XCD = linear%8 = x%8; each XCD's Wf slice is
        // 2 strips x 2MB = 4MB = its L2.  B stream stays L2-resident.
        gemm_kernel<<<dim3(N_ / BN, M_ / BM), 512, 0, stream>>>(xb, Wf, bias, out);
    } else {
        naive_kernel<<<(int)((size_t)M_ * N_ / 256), 256, 0, stream>>>(x, cb, bias, out);
    }
}

// Round 4
// 450.982 us; speedup vs baseline: 1.4539x; 1.0018x over previous
//
#include <hip/hip_runtime.h>
#include <hip/hip_bf16.h>

// Problem constants (fixed by the reference)
constexpr int M_ = 8192;      // batch
constexpr int N_ = 4096;      // out_dim
constexpr int K_ = 4096;      // in_dim
constexpr int CBOOK = 65536;
constexpr int HA = 10007, HB = 20011;
constexpr int HC3 = 3 * 40009;     // 120027
// sign hash: all constants odd => sign = +1 iff (o+i) even

// Algebra (CBOOK = 2^16, HB odd => invertible mod 2^16):
//   197*HB ≡ HA (mod 2^16)  =>  idx(n,k) = (U*HB + HC3) & 0xFFFF,
//   U = (197n + k) & 0xFFFF; parity(U) = parity(n+k) => sign folds into U.
//   W[n][k] = P2ext[(197n+k) & 0xFFFF],
//   P2ext[u] = (u&1 ? -1 : +1) * cb[(u*HB + HC3) & 0xFFFF]   (65536-periodic)
// Used ONLY in prep (one aligned 16B load per output slot instead of 8
// scattered cb gathers); the GEMM reads a linear pre-swizzled W image.
constexpr int C0 = 197;

constexpr int BM = 256, BN = 256, BK = 32;
constexpr int NKT = K_ / BK;               // 128 K-tiles

using bf16x8 = __bf16 __attribute__((ext_vector_type(8)));
using f32x4  = float __attribute__((ext_vector_type(4)));
using u16x8  = unsigned short __attribute__((ext_vector_type(8)));

typedef __attribute__((address_space(3))) void lds_void_t;
typedef const __attribute__((address_space(1))) void gbl_void_t;

static __device__ __forceinline__ unsigned short f2bf(float f) {
    __bf16 h = (__bf16)f;   // RNE on gfx950
    return __builtin_bit_cast(unsigned short, h);
}

// ---------------------------------------------------------------------------
// prep stage 1: P2 phase-copy table  P2p[p][i] = P2ext[i+p], p<8, i<65536.
// 1 MiB; gives every (lane,slot) a 16B-aligned contiguous window of P2ext.
// ---------------------------------------------------------------------------
constexpr int P2N   = 8 * 65536;           // 524288 elems, 1 MiB
constexpr int P2B   = P2N / 256;           // 2048 blocks

__global__ __launch_bounds__(256) void prep_p2(const float* __restrict__ cb,
                                               unsigned short* __restrict__ P2p) {
    const int t = blockIdx.x * 256 + threadIdx.x;   // [0, 2^19)
    const int p = t >> 16;
    const int i = t & 65535;
    const int u = i + p;                            // u*HB < 2^31
    float v = cb[(u * HB + HC3) & (CBOOK - 1)];
    if (u & 1) v = -v;
    P2p[t] = f2bf(v);
}

// ---------------------------------------------------------------------------
// prep stage 2 (merged):
//   blocks [0, GENB): W in LDS-image order (swizzle baked in), via P2p:
//     slot t: row = (t&1023)>>2, blk = t&3, kt = (t>>10)&127, nb = t>>17
//     key = (row>>1)&3; n = nb*256+row; k0 = kt*32 + ((blk^key)<<3)
//     u0 = (197n + k0) & 0xFFFF;  out[j] = P2ext[u0+j] = P2p[u0&7][u0&~7 + j]
//   blocks [GENB, GENB+CONVB): x fp32 -> bf16 row-major (A staging source)
// ---------------------------------------------------------------------------
constexpr int GENB  = N_ * K_ / 8 / 256;   // 8192
constexpr int CONVB = M_ * K_ / 8 / 256;   // 16384

__global__ __launch_bounds__(256) void prep_main(const float* __restrict__ x,
                                                 const unsigned short* __restrict__ P2p,
                                                 unsigned short* __restrict__ Wf,
                                                 unsigned short* __restrict__ xb) {
    const int b = blockIdx.x;
    if (b < GENB) {
        const int t    = b * 256 + threadIdx.x;   // [0, 2^21) 16B slots
        const int slot = t & 1023;
        const int kt   = (t >> 10) & 127;
        const int nb   = t >> 17;
        const int row  = slot >> 2;
        const int key  = (row >> 1) & 3;
        const int n  = (nb << 8) + row;
        const int k0 = (kt << 5) + (((slot & 3) ^ key) << 3);
        const int u0 = (C0 * n + k0) & (CBOOK - 1);
        const u16x8 w = *reinterpret_cast<const u16x8*>(
            P2p + ((u0 & 7) << 16) + (u0 & 65528));     // one aligned 16B load
        *reinterpret_cast<u16x8*>(&Wf[(size_t)t * 8]) = w;   // coalesced
    } else {
        const size_t t = (size_t)(b - GENB) * 256 + threadIdx.x;
        const float4* p = reinterpret_cast<const float4*>(x) + t * 2;
        const float4 a = p[0], c = p[1];
        u16x8 out;
        out[0] = f2bf(a.x); out[1] = f2bf(a.y); out[2] = f2bf(a.z); out[3] = f2bf(a.w);
        out[4] = f2bf(c.x); out[5] = f2bf(c.y); out[6] = f2bf(c.z); out[7] = f2bf(c.w);
        reinterpret_cast<u16x8*>(xb)[t] = out;
    }
}

// ---------------------------------------------------------------------------
// GEMM: C[M][N] = A[M][K] * W[N][K]^T + bias
// 256x256 tile, BK=32, 512 threads (8 waves 2Mx4N, wave tile 128x64).
// 4-deep LDS ring (128 KB).  Schedule per window kt (ONE barrier/window):
//   vmcnt(4) cert [stage(kt+1) landed] -> s_barrier -> STAGE(kt+3)
//   -> MFMA(kt) on fragments read LAST window -> tail ds_reads of frags(kt+1)
// Tail reads fly across the barrier and hide under next window's MFMA issue;
// MFMA never waits on fresh LDS reads.  Stage never drained below vmcnt(4)
// except once at kt=NKT-2.  Old frag regs die before tail reads -> no VGPR
// double-buffer cost (launch_bounds(512,2) caps allocator at 256).
// ---------------------------------------------------------------------------
__global__ __launch_bounds__(512, 2) void gemm_kernel(
        const unsigned short* __restrict__ A,    // xb row-major [M][K]
        const unsigned short* __restrict__ Wf,   // LDS-image W
        const float* __restrict__ bias,
        float* __restrict__ C) {
    __shared__ __align__(16) unsigned short sm[4 * 8192 * 2];  // 128 KB
    unsigned short* As = sm;                 // [4][8192]
    unsigned short* Bs = sm + 4 * 8192;      // [4][8192]

    const int tid  = threadIdx.x;
    const int lane = tid & 63;
    const int w    = tid >> 6;          // wave 0..7
    const int wm   = w >> 2;            // 0..1 -> rows wm*128
    const int wn   = w & 3;             // 0..3 -> cols wn*64
    const int m0 = blockIdx.y * BM;
    const int n0 = blockIdx.x * BN;

    const int quad = lane >> 4;         // 0..3
    const int l16  = lane & 15;

    // --- staging addressing (slot s = r*512 + tid: row=s>>2, blk=s&3,
    //     swizzle key=(row>>1)&3 baked into both source layouts) ---
    const int sblk = (lane & 3) ^ ((lane >> 3) & 3);
    const unsigned short* aLane =
        A + (size_t)(m0 + w * 16 + (lane >> 2)) * K_ + sblk * 8;
    const unsigned short* bLane =
        Wf + (size_t)blockIdx.x * NKT * 8192 + tid * 8;   // fully linear

    // --- ds-read addressing (swizzled, 2-way max -> conflict-free) ---
    const int rblk = (quad ^ ((l16 >> 1) & 3)) * 8;
    const unsigned short* aRd = As + (wm * 128 + l16) * 32 + rblk;
    const unsigned short* bRd = Bs + (wn * 64 + l16) * 32 + rblk;

    f32x4 acc[8][4] = {};               // wave tile 128x64 (AGPRs)
    bf16x8 bfr[4], afr[8];              // current window's fragments

    // stage K-tile kt into ring slot bs (4 vmem loads per wave)
    auto STAGE = [&](int kt, int bs) {
#pragma unroll
        for (int r = 0; r < 2; ++r) {
            __builtin_amdgcn_global_load_lds(
                (gbl_void_t*)(aLane + (size_t)r * 128 * K_ + (size_t)kt * BK),
                (lds_void_t*)(As + bs * 8192 + (r * 512 + w * 64) * 8), 16, 0, 0);
            __builtin_amdgcn_global_load_lds(
                (gbl_void_t*)(bLane + (size_t)kt * 8192 + r * 4096),
                (lds_void_t*)(Bs + bs * 8192 + (r * 512 + w * 64) * 8), 16, 0, 0);
        }
    };
    // read the 12 fragments of K-tile kt into registers
    auto READF = [&](int kt) {
        const int bs = kt & 3;
#pragma unroll
        for (int nt = 0; nt < 4; ++nt)
            bfr[nt] = *reinterpret_cast<const bf16x8*>(bRd + bs * 8192 + nt * 512);
#pragma unroll
        for (int mt = 0; mt < 8; ++mt)
            afr[mt] = *reinterpret_cast<const bf16x8*>(aRd + bs * 8192 + mt * 512);
    };

    STAGE(0, 0); STAGE(1, 1); STAGE(2, 2);
    asm volatile("s_waitcnt vmcnt(8)" ::: "memory");   // stage(0) landed
    __builtin_amdgcn_s_barrier();
    __builtin_amdgcn_sched_barrier(0);
    READF(0);
    __builtin_amdgcn_sched_barrier(0);

    for (int kt = 0; kt < NKT; ++kt) {
        // certify stage(kt+1) landed; keep stage(kt+2) (4 loads) in flight
        if (kt + 2 < NKT)      asm volatile("s_waitcnt vmcnt(4)" ::: "memory");
        else if (kt + 1 < NKT) asm volatile("s_waitcnt vmcnt(0)" ::: "memory");
        __builtin_amdgcn_s_barrier();            // open window kt
        __builtin_amdgcn_sched_barrier(0);

        if (kt + 3 < NKT) STAGE(kt + 3, (kt + 3) & 3);
        __builtin_amdgcn_sched_barrier(0);

        __builtin_amdgcn_s_setprio(1);
#pragma unroll
        for (int mt = 0; mt < 8; ++mt)
#pragma unroll
            for (int nt = 0; nt < 4; ++nt)
                acc[mt][nt] = __builtin_amdgcn_mfma_f32_16x16x32_bf16(
                    afr[mt], bfr[nt], acc[mt][nt], 0, 0, 0);
        __builtin_amdgcn_s_setprio(0);
        __builtin_amdgcn_sched_barrier(0);

        if (kt + 1 < NKT) READF(kt + 1);         // tail reads: fly across the
        __builtin_amdgcn_sched_barrier(0);       // barrier, land under MFMA(kt+1)
    }

    // epilogue: C/D layout col=lane&15, row=quad*4+r (m89/m91-verified)
#pragma unroll
    for (int nt = 0; nt < 4; ++nt) {
        const int col = n0 + wn * 64 + nt * 16 + l16;
        const float bv = bias[col];
#pragma unroll
        for (int mt = 0; mt < 8; ++mt) {
            const int rowb = m0 + wm * 128 + mt * 16 + quad * 4;
#pragma unroll
            for (int r = 0; r < 4; ++r)
                C[(size_t)(rowb + r) * N_ + col] = acc[mt][nt][r] + bv;
        }
    }
}

// ---------------------------------------------------------------------------
// Correctness-insurance fallback (only if ws too small; slow but exact)
// ---------------------------------------------------------------------------
__global__ __launch_bounds__(256) void naive_kernel(const float* __restrict__ x,
                                                    const float* __restrict__ cb,
                                                    const float* __restrict__ bias,
                                                    float* __restrict__ out) {
    const size_t t = (size_t)blockIdx.x * 256 + threadIdx.x;
    const int row = (int)(t / N_);
    const int col = (int)(t % N_);
    float s = bias[col];
    const float* xr = x + (size_t)row * K_;
    const int h = col * HA + HC3;
    for (int i = 0; i < K_; ++i) {
        float v = cb[(h + i * HB) & (CBOOK - 1)];
        s += xr[i] * (((col ^ i) & 1) ? -v : v);
    }
    out[t] = s;
}

extern "C" void kernel_launch(void* const* d_in, const int* in_sizes, int n_in,
                              void* d_out, int out_size, void* d_ws, size_t ws_size,
                              hipStream_t stream) {
    const float* x    = (const float*)d_in[0];
    const float* cb   = (const float*)d_in[1];
    const float* bias = (const float*)d_in[2];
    float* out = (float*)d_out;

    const size_t wBytes = (size_t)N_ * K_ * sizeof(unsigned short);  // 32 MiB
    const size_t xBytes = (size_t)M_ * K_ * sizeof(unsigned short);  // 64 MiB
    const size_t pBytes = (size_t)P2N * sizeof(unsigned short);      // 1 MiB

    if (ws_size >= wBytes + xBytes + pBytes) {
        unsigned short* Wf  = (unsigned short*)d_ws;
        unsigned short* xb  = (unsigned short*)((char*)d_ws + wBytes);
        unsigned short* P2p = (unsigned short*)((char*)d_ws + wBytes + xBytes);
        prep_p2<<<P2B, 256, 0, stream>>>(cb, P2p);
        prep_main<<<GENB + CONVB, 256, 0, stream>>>(x, P2p, Wf, xb);
        // grid x = 16 n-strips: XCD = linear%8 = x%8; each XCD's Wf slice is
        // 2 strips x 2MB = 4MB = its L2.  B stream stays L2-resident.
        gemm_kernel<<<dim3(N_ / BN, M_ / BM), 512, 0, stream>>>(xb, Wf, bias, out);
    } else {
        naive_kernel<<<(int)((size_t)M_ * N_ / 256), 256, 0, stream>>>(x, cb, bias, out);
    }
}

// Round 6
// 447.653 us; speedup vs baseline: 1.4647x; 1.0074x over previous
//
#include <hip/hip_runtime.h>
#include <hip/hip_bf16.h>

// Problem constants (fixed by the reference)
constexpr int M_ = 8192;      // batch
constexpr int N_ = 4096;      // out_dim
constexpr int K_ = 4096;      // in_dim
constexpr int CBOOK = 65536;
constexpr int HA = 10007, HB = 20011;
constexpr int HC3 = 3 * 40009;     // 120027
// sign hash: all constants odd => sign = +1 iff (o+i) even

// Algebra (CBOOK = 2^16, HB odd => invertible mod 2^16):
//   197*HB ≡ HA (mod 2^16)  =>  idx(n,k) = (U*HB + HC3) & 0xFFFF,
//   U = (197n + k) & 0xFFFF; parity(U) = parity(n+k) => sign folds into U.
//   W[n][k] = P2ext[(197n+k) & 0xFFFF],
//   P2ext[u] = (u&1 ? -1 : +1) * cb[(u*HB + HC3) & 0xFFFF]   (65536-periodic)
// Used ONLY in prep (one aligned 16B load per output slot instead of 8
// scattered cb gathers); the GEMM reads a linear pre-swizzled W image.
constexpr int C0 = 197;

constexpr int BM = 256, BN = 256, BK = 32;
constexpr int NKT = K_ / BK;               // 128 K-tiles

using bf16x8 = __bf16 __attribute__((ext_vector_type(8)));
using f32x4  = float __attribute__((ext_vector_type(4)));
using u16x8  = unsigned short __attribute__((ext_vector_type(8)));

typedef __attribute__((address_space(3))) void lds_void_t;
typedef const __attribute__((address_space(1))) void gbl_void_t;

static __device__ __forceinline__ unsigned short f2bf(float f) {
    __bf16 h = (__bf16)f;   // RNE on gfx950
    return __builtin_bit_cast(unsigned short, h);
}

// ---------------------------------------------------------------------------
// prep stage 1: P2 phase-copy table  P2p[p][i] = P2ext[i+p], p<8, i<65536.
// 1 MiB; gives every (lane,slot) a 16B-aligned contiguous window of P2ext.
// ---------------------------------------------------------------------------
constexpr int P2N   = 8 * 65536;           // 524288 elems, 1 MiB
constexpr int P2B   = P2N / 256;           // 2048 blocks

__global__ __launch_bounds__(256) void prep_p2(const float* __restrict__ cb,
                                               unsigned short* __restrict__ P2p) {
    const int t = blockIdx.x * 256 + threadIdx.x;   // [0, 2^19)
    const int p = t >> 16;
    const int i = t & 65535;
    const int u = i + p;                            // u*HB < 2^31
    float v = cb[(u * HB + HC3) & (CBOOK - 1)];
    if (u & 1) v = -v;
    P2p[t] = f2bf(v);
}

// ---------------------------------------------------------------------------
// prep stage 2 (merged):
//   blocks [0, GENB): W in LDS-image order (swizzle baked in), via P2p:
//     slot t: row = (t&1023)>>2, blk = t&3, kt = (t>>10)&127, nb = t>>17
//     key = (row>>1)&3; n = nb*256+row; k0 = kt*32 + ((blk^key)<<3)
//     u0 = (197n + k0) & 0xFFFF;  out[j] = P2ext[u0+j] = P2p[u0&7][u0&~7 + j]
//   blocks [GENB, GENB+CONVB): x fp32 -> bf16 row-major (A staging source)
// ---------------------------------------------------------------------------
constexpr int GENB  = N_ * K_ / 8 / 256;   // 8192
constexpr int CONVB = M_ * K_ / 8 / 256;   // 16384

__global__ __launch_bounds__(256) void prep_main(const float* __restrict__ x,
                                                 const unsigned short* __restrict__ P2p,
                                                 unsigned short* __restrict__ Wf,
                                                 unsigned short* __restrict__ xb) {
    const int b = blockIdx.x;
    if (b < GENB) {
        const int t    = b * 256 + threadIdx.x;   // [0, 2^21) 16B slots
        const int slot = t & 1023;
        const int kt   = (t >> 10) & 127;
        const int nb   = t >> 17;
        const int row  = slot >> 2;
        const int key  = (row >> 1) & 3;
        const int n  = (nb << 8) + row;
        const int k0 = (kt << 5) + (((slot & 3) ^ key) << 3);
        const int u0 = (C0 * n + k0) & (CBOOK - 1);
        const u16x8 w = *reinterpret_cast<const u16x8*>(
            P2p + ((u0 & 7) << 16) + (u0 & 65528));     // one aligned 16B load
        *reinterpret_cast<u16x8*>(&Wf[(size_t)t * 8]) = w;   // coalesced
    } else {
        const size_t t = (size_t)(b - GENB) * 256 + threadIdx.x;
        const float4* p = reinterpret_cast<const float4*>(x) + t * 2;
        const float4 a = p[0], c = p[1];
        u16x8 out;
        out[0] = f2bf(a.x); out[1] = f2bf(a.y); out[2] = f2bf(a.z); out[3] = f2bf(a.w);
        out[4] = f2bf(c.x); out[5] = f2bf(c.y); out[6] = f2bf(c.z); out[7] = f2bf(c.w);
        reinterpret_cast<u16x8*>(xb)[t] = out;
    }
}

// ---------------------------------------------------------------------------
// GEMM: C[M][N] = A[M][K] * W[N][K]^T + bias
// 256x256 tile, BK=32, 512 threads (8 waves 2Mx4N, wave tile 128x64).
// 4-deep LDS ring (128 KB).  Schedule per window kt (ONE barrier/window):
//   vmcnt(4) cert [stage(kt+1) landed] -> s_barrier -> STAGE(kt+3)
//   -> MFMA cluster with afr[mt] reloads for kt+1 INTERLEAVED (afr[mt] is
//      dead after its 4 MFMAs -> register-neutral reload; reads certified
//      since slot (kt+1)&3 landed at this window's open)
//   -> 4-read bfr tail (bfr is live through the cluster; no reg headroom at
//      128 VGPR + 128 AGPR = 256/wave for double-buffering it)
// Loop unrolled x4 so ring-slot offsets are compile-time immediates (no
// runtime ring VALU).  No sched_barrier fences: ds_reads are compiler-
// visible loads; memory ops can't cross the "memory"-clobbered waitcnts or
// s_barrier, and correctness doesn't depend on scheduling order.
// Cross-wave LDS WAR is safe: a wave's reads of slot (kt+1)&3 retire before
// its MFMAs(kt+1) (lgkm), hence before it reaches barrier(kt+2), hence
// before any wave issues STAGE(kt+5) which is the next writer of that slot.
// ---------------------------------------------------------------------------
__global__ __launch_bounds__(512, 2) void gemm_kernel(
        const unsigned short* __restrict__ A,    // xb row-major [M][K]
        const unsigned short* __restrict__ Wf,   // LDS-image W
        const float* __restrict__ bias,
        float* __restrict__ C) {
    __shared__ __align__(16) unsigned short sm[4 * 8192 * 2];  // 128 KB
    unsigned short* As = sm;                 // [4][8192]
    unsigned short* Bs = sm + 4 * 8192;      // [4][8192]

    const int tid  = threadIdx.x;
    const int lane = tid & 63;
    const int w    = tid >> 6;          // wave 0..7
    const int wm   = w >> 2;            // 0..1 -> rows wm*128
    const int wn   = w & 3;             // 0..3 -> cols wn*64
    const int m0 = blockIdx.y * BM;
    const int n0 = blockIdx.x * BN;

    const int quad = lane >> 4;         // 0..3
    const int l16  = lane & 15;

    // --- staging addressing (slot s = r*512 + tid: row=s>>2, blk=s&3,
    //     swizzle key=(row>>1)&3 baked into both source layouts) ---
    const int sblk = (lane & 3) ^ ((lane >> 3) & 3);
    const unsigned short* aLane =
        A + (size_t)(m0 + w * 16 + (lane >> 2)) * K_ + sblk * 8;
    const unsigned short* bLane =
        Wf + (size_t)blockIdx.x * NKT * 8192 + tid * 8;   // fully linear

    // --- ds-read addressing (swizzled, 2-way max -> conflict-free) ---
    const int rblk = (quad ^ ((l16 >> 1) & 3)) * 8;
    const unsigned short* aRd = As + (wm * 128 + l16) * 32 + rblk;
    const unsigned short* bRd = Bs + (wn * 64 + l16) * 32 + rblk;

    f32x4 acc[8][4] = {};               // wave tile 128x64 (AGPRs)
    bf16x8 bfr[4], afr[8];              // current window's fragments

    // stage K-tile kt into ring slot bs (4 vmem loads per wave)
    auto STAGE = [&](int kt, int bs) {
#pragma unroll
        for (int r = 0; r < 2; ++r) {
            __builtin_amdgcn_global_load_lds(
                (gbl_void_t*)(aLane + (size_t)r * 128 * K_ + (size_t)kt * BK),
                (lds_void_t*)(As + bs * 8192 + (r * 512 + w * 64) * 8), 16, 0, 0);
            __builtin_amdgcn_global_load_lds(
                (gbl_void_t*)(bLane + (size_t)kt * 8192 + r * 4096),
                (lds_void_t*)(Bs + bs * 8192 + (r * 512 + w * 64) * 8), 16, 0, 0);
        }
    };

    STAGE(0, 0); STAGE(1, 1); STAGE(2, 2);
    asm volatile("s_waitcnt vmcnt(8)" ::: "memory");   // stage(0) landed
    __builtin_amdgcn_s_barrier();
    // preload fragments of K-tile 0 (slot 0)
#pragma unroll
    for (int nt = 0; nt < 4; ++nt)
        bfr[nt] = *reinterpret_cast<const bf16x8*>(bRd + nt * 512);
#pragma unroll
    for (int mt = 0; mt < 8; ++mt)
        afr[mt] = *reinterpret_cast<const bf16x8*>(aRd + mt * 512);

    for (int kt0 = 0; kt0 < NKT; kt0 += 4) {
#pragma unroll
        for (int s = 0; s < 4; ++s) {
            const int kt = kt0 + s;
            // certify stage(kt+1) landed; keep stage(kt+2) (4 loads) in flight
            if (kt + 2 < NKT)      asm volatile("s_waitcnt vmcnt(4)" ::: "memory");
            else if (kt + 1 < NKT) asm volatile("s_waitcnt vmcnt(0)" ::: "memory");
            __builtin_amdgcn_s_barrier();            // open window kt

            if (kt + 3 < NKT) STAGE(kt + 3, (s + 3) & 3);

            const int rs = ((s + 1) & 3) * 8192;     // reload slot (imm offs)
            __builtin_amdgcn_s_setprio(1);
#pragma unroll
            for (int mt = 0; mt < 8; ++mt) {
#pragma unroll
                for (int nt = 0; nt < 4; ++nt)
                    acc[mt][nt] = __builtin_amdgcn_mfma_f32_16x16x32_bf16(
                        afr[mt], bfr[nt], acc[mt][nt], 0, 0, 0);
                // afr[mt] dead now: reload for window kt+1 (interleaves with
                // remaining MFMAs; at kt=NKT-1 reads stale data, never used)
                afr[mt] = *reinterpret_cast<const bf16x8*>(aRd + rs + mt * 512);
            }
            __builtin_amdgcn_s_setprio(0);
            // bfr tail reload (4 reads; latency covered by next barrier+stage)
#pragma unroll
            for (int nt = 0; nt < 4; ++nt)
                bfr[nt] = *reinterpret_cast<const bf16x8*>(bRd + rs + nt * 512);
        }
    }

    // epilogue: C/D layout col=lane&15, row=quad*4+r (m89/m91-verified)
#pragma unroll
    for (int nt = 0; nt < 4; ++nt) {
        const int col = n0 + wn * 64 + nt * 16 + l16;
        const float bv = bias[col];
#pragma unroll
        for (int mt = 0; mt < 8; ++mt) {
            const int rowb = m0 + wm * 128 + mt * 16 + quad * 4;
#pragma unroll
            for (int r = 0; r < 4; ++r)
                C[(size_t)(rowb + r) * N_ + col] = acc[mt][nt][r] + bv;
        }
    }
}

// ---------------------------------------------------------------------------
// Correctness-insurance fallback (only if ws too small; slow but exact)
// ---------------------------------------------------------------------------
__global__ __launch_bounds__(256) void naive_kernel(const float* __restrict__ x,
                                                    const float* __restrict__ cb,
                                                    const float* __restrict__ bias,
                                                    float* __restrict__ out) {
    const size_t t = (size_t)blockIdx.x * 256 + threadIdx.x;
    const int row = (int)(t / N_);
    const int col = (int)(t % N_);
    float s = bias[col];
    const float* xr = x + (size_t)row * K_;
    const int h = col * HA + HC3;
    for (int i = 0; i < K_; ++i) {
        float v = cb[(h + i * HB) & (CBOOK - 1)];
        s += xr[i] * (((col ^ i) & 1) ? -v : v);
    }
    out[t] = s;
}

extern "C" void kernel_launch(void* const* d_in, const int* in_sizes, int n_in,
                              void* d_out, int out_size, void* d_ws, size_t ws_size,
                              hipStream_t stream) {
    const float* x    = (const float*)d_in[0];
    const float* cb   = (const float*)d_in[1];
    const float* bias = (const float*)d_in[2];
    float* out = (float*)d_out;

    const size_t wBytes = (size_t)N_ * K_ * sizeof(unsigned short);  // 32 MiB
    const size_t xBytes = (size_t)M_ * K_ * sizeof(unsigned short);  // 64 MiB
    const size_t pBytes = (size_t)P2N * sizeof(unsigned short);      // 1 MiB

    if (ws_size >= wBytes + xBytes + pBytes) {
        unsigned short* Wf  = (unsigned short*)d_ws;
        unsigned short* xb  = (unsigned short*)((char*)d_ws + wBytes);
        unsigned short* P2p = (unsigned short*)((char*)d_ws + wBytes + xBytes);
        prep_p2<<<P2B, 256, 0, stream>>>(cb, P2p);
        prep_main<<<GENB + CONVB, 256, 0, stream>>>(x, P2p, Wf, xb);
        // grid x = 16 n-strips: XCD = linear%8 = x%8; each XCD's Wf slice is
        // 2 strips x 2MB = 4MB = its L2.  B stream stays L2-resident.
        gemm_kernel<<<dim3(N_ / BN, M_ / BM), 512, 0, stream>>>(xb, Wf, bias, out);
    } else {
        naive_kernel<<<(int)((size_t)M_ * N_ / 256), 256, 0, stream>>>(x, cb, bias, out);
    }
}